// Round 2
// baseline (515.525 us; speedup 1.0000x reference)
//
#include <hip/hip_runtime.h>

// Problem constants: image (C,H,W) fp32, flow (2,H,W) fp32.
constexpr int C  = 32;
constexpr int H  = 1024;
constexpr int W  = 2048;
constexpr int HW = H * W;

constexpr int TW = 64;              // tile width  (pixels)
constexpr int TH = 32;              // tile height (pixels)
constexpr int MC = 4;               // col margin each side (covers |flow_u|<=3 worst-case edge px)
constexpr int MR = 4;               // row margin each side
constexpr int SC = TW + 2 * MC;     // 72 staged cols
constexpr int SR = TH + 2 * MR;     // 40 staged rows
constexpr int SLOTS = SR * (SC / 4);// 720 float4 staging slots
constexpr int NSLOT = (SLOTS + 255) / 256; // 3 slots max per thread
constexpr int NPX = (TW * TH) / 256;// 8 pixels per thread

constexpr int CPB = 8;              // channels per block (channel-split)
constexpr int ZB  = C / CPB;        // 4 z-groups
constexpr int GX  = W / TW;         // 32
constexpr int GY  = H / TH;         // 32
constexpr int NWG = GX * GY * ZB;   // 4096 blocks

__global__ __launch_bounds__(256) void warp_kernel(
    const float* __restrict__ image,
    const float* __restrict__ flow,
    float* __restrict__ out)
{
    __shared__ float lsbuf[2][SR * SC];   // 2 x 11520 B = 23040 B -> 7 blocks/CU

    // ---- bijective XCD chunking: XCD x owns flat ids {x, x+8, ...} -> contiguous nid chunk
    const int flat = blockIdx.x;                       // 0..4095
    const int nid  = (flat & 7) * (NWG / 8) + (flat >> 3);
    const int bx   = nid & (GX - 1);
    const int by   = (nid / GX) & (GY - 1);
    const int bz   = nid / (GX * GY);

    const int tid = threadIdx.x;
    const int tx0 = bx * TW;
    const int ty0 = by * TH;
    const int c0  = bz * CPB;

    // ---- staging slot address precompute (channel-invariant) ----
    // slot s -> staged row r = s/(SC/4), col group c4 = (s%(SC/4))*4
    int s_srowW[NSLOT], s_scol[NSLOT], s_lds[NSLOT];
    bool s_colok[NSLOT];
    #pragma unroll
    for (int k = 0; k < NSLOT; ++k) {
        const int s = tid + 256 * k;
        if (s < SLOTS) {
            const int r    = s / (SC / 4);
            const int c4   = (s - r * (SC / 4)) * 4;
            const int srow = min(max(ty0 - MR + r, 0), H - 1); // row clamp
            const int scol = tx0 - MC + c4;
            s_srowW[k] = srow * W;
            s_scol[k]  = scol;
            s_lds[k]   = r * SC + c4;
            s_colok[k] = (scol >= 0) && (scol + 3 < W);
        } else {
            s_srowW[k] = -1;  // only possible for last k
        }
    }

    auto stage_load = [&](int c, float4* vals) {
        const float* __restrict__ imgc = image + (size_t)c * HW;
        #pragma unroll
        for (int k = 0; k < NSLOT; ++k) {
            if (k == NSLOT - 1 && s_srowW[k] < 0) continue;
            if (s_colok[k]) {
                vals[k] = *(const float4*)(imgc + s_srowW[k] + s_scol[k]);
            } else {   // edge-column tiles: per-element clamped gather
                float4 t;
                t.x = imgc[s_srowW[k] + min(max(s_scol[k] + 0, 0), W - 1)];
                t.y = imgc[s_srowW[k] + min(max(s_scol[k] + 1, 0), W - 1)];
                t.z = imgc[s_srowW[k] + min(max(s_scol[k] + 2, 0), W - 1)];
                t.w = imgc[s_srowW[k] + min(max(s_scol[k] + 3, 0), W - 1)];
                vals[k] = t;
            }
        }
    };
    auto stage_write = [&](int b, const float4* vals) {
        #pragma unroll
        for (int k = 0; k < NSLOT; ++k) {
            if (k == NSLOT - 1 && s_srowW[k] < 0) continue;
            *(float4*)&lsbuf[b][s_lds[k]] = vals[k];
        }
    };

    // ---- issue first stage early: HBM latency overlaps flow reads below ----
    float4 vals[NSLOT];
    stage_load(c0, vals);

    // ---- per-pixel precompute (channel-invariant): weights + LDS addr ----
    const int tx  = tid & (TW - 1);
    const int tyq = tid >> 6;                 // 0..3
    const int xpx = tx0 + tx;
    const int po0 = (ty0 + tyq) * W + xpx;    // pixel flat offset, row stride 4*W per i

    float w00[NPX], w10[NPX], w01[NPX], w11[NPX];
    int addr0[NPX];
    unsigned fmask = 0;

    #pragma unroll
    for (int i = 0; i < NPX; ++i) {
        const int po  = po0 + i * 4 * W;
        const int ypx = ty0 + tyq + 4 * i;
        const float u = (float)xpx + flow[po];
        const float v = (float)ypx + flow[HW + po];
        const float u0f = floorf(u);
        const float v0f = floorf(v);
        const float wu = u - u0f;
        const float wv = v - v0f;
        const int u0 = (int)u0f;
        const int v0 = (int)v0f;

        const bool vu0 = (u0 >= 0) & (u0 <= W - 1);
        const bool vu1 = (u0 + 1 >= 0) & (u0 + 1 <= W - 1);
        const bool vv0 = (v0 >= 0) & (v0 <= H - 1);
        const bool vv1 = (v0 + 1 >= 0) & (v0 + 1 <= H - 1);

        // Fold validity into weights: w * where(valid,g,0) == (valid?w:0)*g_clamped.
        float a = (1.0f - wu) * (1.0f - wv);
        float b = wu * (1.0f - wv);
        float c = (1.0f - wu) * wv;
        float d = wu * wv;
        w00[i] = (vv0 & vu0) ? a : 0.0f;
        w10[i] = (vv0 & vu1) ? b : 0.0f;
        w01[i] = (vv1 & vu0) ? c : 0.0f;
        w11[i] = (vv1 & vu1) ? d : 0.0f;

        // Fast path iff the 2x2 footprint lies inside the staged window.
        const bool fast = (u0 >= tx0 - MC) & (u0 <= tx0 + TW + MC - 2) &
                          (v0 >= ty0 - MR) & (v0 <= ty0 + TH + MR - 2);
        fmask |= (fast ? 1u : 0u) << i;
        addr0[i] = (v0 - ty0 + MR) * SC + (u0 - tx0 + MC);
    }

    // ---- channel loop: double-buffered staging, one barrier per channel ----
    stage_write(0, vals);
    __syncthreads();

    for (int cc = 0; cc < CPB; ++cc) {
        const int c = c0 + cc;
        if (cc + 1 < CPB) stage_load(c + 1, vals);   // loads in flight over compute

        const float* __restrict__ ls = lsbuf[cc & 1];
        const float* __restrict__ imgc = image + (size_t)c * HW;
        float* __restrict__ outc = out + (size_t)c * HW;

        #pragma unroll
        for (int i = 0; i < NPX; ++i) {
            const int po = po0 + i * 4 * W;
            float r;
            if ((fmask >> i) & 1u) {
                const int a0 = addr0[i];
                const float g00 = ls[a0];
                const float g10 = ls[a0 + 1];
                const float g01 = ls[a0 + SC];
                const float g11 = ls[a0 + SC + 1];
                r = w00[i] * g00 + w10[i] * g10 + w01[i] * g01 + w11[i] * g11;
            } else {
                // Rare outlier (|flow| beyond margin): global clamped fallback.
                const int ypx = ty0 + tyq + 4 * i;
                const float u = (float)xpx + flow[po];
                const float v = (float)ypx + flow[HW + po];
                const int u0 = (int)floorf(u);
                const int v0 = (int)floorf(v);
                const int u0c = min(max(u0, 0), W - 1);
                const int u1c = min(max(u0 + 1, 0), W - 1);
                const int v0c = min(max(v0, 0), H - 1);
                const int v1c = min(max(v0 + 1, 0), H - 1);
                r = w00[i] * imgc[v0c * W + u0c] + w10[i] * imgc[v0c * W + u1c]
                  + w01[i] * imgc[v1c * W + u0c] + w11[i] * imgc[v1c * W + u1c];
            }
            // Output is never re-read: keep it from evicting image lines.
            __builtin_nontemporal_store(r, &outc[po]);
        }

        if (cc + 1 < CPB) {
            stage_write((cc + 1) & 1, vals);
            __syncthreads();
        }
    }
}

extern "C" void kernel_launch(void* const* d_in, const int* in_sizes, int n_in,
                              void* d_out, int out_size, void* d_ws, size_t ws_size,
                              hipStream_t stream) {
    const float* image = (const float*)d_in[0];
    const float* flow  = (const float*)d_in[1];
    float* out = (float*)d_out;

    warp_kernel<<<dim3(NWG), 256, 0, stream>>>(image, flow, out);
}